// Round 18
// baseline (80.795 us; speedup 1.0000x reference)
//
#include <hip/hip_runtime.h>
#include <hip/hip_bf16.h>

#define TT  2048
#define NH  32
#define NKV 8
#define DD  128
#define KVB 128         // keys per LDS tile
#define THR 8.0f        // defer-max rescale threshold (T13)

typedef __attribute__((ext_vector_type(8)))  short  short8;
typedef __attribute__((ext_vector_type(4)))  float  f32x4;
typedef __attribute__((ext_vector_type(16))) float  f32x16;
typedef unsigned int u32;
typedef __attribute__((ext_vector_type(4)))  u32    u32x4;

static __device__ __forceinline__ short f2bf(float x) {
  __bf16 b = (__bf16)x;                 // RNE f32->bf16
  return __builtin_bit_cast(short, b);
}
static __device__ __forceinline__ short8 cvt8(f32x4 a, f32x4 b) {
  short8 r;
  r[0]=f2bf(a[0]); r[1]=f2bf(a[1]); r[2]=f2bf(a[2]); r[3]=f2bf(a[3]);
  r[4]=f2bf(b[0]); r[5]=f2bf(b[1]); r[6]=f2bf(b[2]); r[7]=f2bf(b[3]);
  return r;
}
static __device__ __forceinline__ u32 pk2(float lo, float hi) {
  const u32 a = (u32)(unsigned short)f2bf(lo);
  const u32 b = (u32)(unsigned short)f2bf(hi);
  return a | (b << 16);
}
static __device__ __forceinline__ void gload_lds16(const short* g, short* l) {
  __builtin_amdgcn_global_load_lds(
      (const __attribute__((address_space(1))) u32*)g,
      (__attribute__((address_space(3))) u32*)l, 16, 0, 0);
}

// ---------------- pre-pass: K -> bf16 [kvh][j][d]; V -> bf16 transposed [kvh][d][j] ----
__global__ __launch_bounds__(256) void preconv(
    const float* __restrict__ K, const float* __restrict__ V,
    short* __restrict__ Kbf, short* __restrict__ Vtbf)
{
  const int t = threadIdx.x;
  if (blockIdx.x >= 256) {
    const int b  = blockIdx.x - 256;
    const int rr = (b << 6) + (t >> 2);      // rr = j*8+kvh
    const int q  = t & 3;
    const int j = rr >> 3, kvh = rr & 7;
    const float* src = K + (size_t)rr * DD + q * 32;
    short* dst = Kbf + ((size_t)kvh * TT + j) * DD + q * 32;
#pragma unroll
    for (int i = 0; i < 4; ++i) {
      f32x4 a  = *reinterpret_cast<const f32x4*>(src + i * 8);
      f32x4 bb = *reinterpret_cast<const f32x4*>(src + i * 8 + 4);
      *reinterpret_cast<short8*>(dst + i * 8) = cvt8(a, bb);
    }
  } else {
    const int kvh = blockIdx.x >> 5, jt = blockIdx.x & 31;
    __shared__ short Vl[64][136];
    const int jl = t >> 2, q = t & 3;
    const float* src = V + ((size_t)(jt * 64 + jl) * NKV + kvh) * DD + q * 32;
#pragma unroll
    for (int i = 0; i < 4; ++i) {
      f32x4 a  = *reinterpret_cast<const f32x4*>(src + i * 8);
      f32x4 bb = *reinterpret_cast<const f32x4*>(src + i * 8 + 4);
      *reinterpret_cast<short8*>(&Vl[jl][q * 32 + i * 8]) = cvt8(a, bb);
    }
    __syncthreads();
    const int d = t >> 1, jh = t & 1;
    short8 o[4];
#pragma unroll
    for (int k = 0; k < 4; ++k)
#pragma unroll
      for (int i = 0; i < 8; ++i)
        o[k][i] = Vl[jh * 32 + k * 8 + i][d];
    short* dst = Vtbf + ((size_t)kvh * DD + d) * TT + jt * 64 + jh * 32;
#pragma unroll
    for (int k = 0; k < 4; ++k)
      *reinterpret_cast<short8*>(dst + k * 8) = o[k];
  }
}

// ---------------- main attention kernel ------------------------------------------
// r14 body (proven 77.6us, reproduced r17) + T4 COUNTED-VMCNT SPLIT DRAIN:
// the single per-tile __syncthreads (which drains ALL 8 DMAs: K+V, 64KB) is
// replaced by two raw barriers with counted waits:
//   barrier A:  s_waitcnt vmcnt(4) -> waits only the 4 K-DMAs (issued first);
//               the 4 V-DMAs stay in flight while QK^T runs (QK reads Kb only).
//   barrier B:  s_waitcnt vmcnt(0) -> V landed before PV reads Vt; the
//               next-tile DMA is issued AFTER barrier B (before it, the
//               vmcnt(0) would drain the fresh issue = full stall).
// Correctness: cross-wave visibility via the barrier (each wave counted-waits
// its OWN DMAs before entering); DMA(t+1) -> buf^1 after barrier B is safe
// because tile t-1's reads of buf^1 retired before barrier A(t); "memory"
// clobbers pin ds_read/gload ordering around the waits (guide rule 18);
// epilogue keeps full __syncthreads. Everything else r14-verbatim: KVB=128,
// 8 waves = 4 heads x 2 key-halves, defer-max THR=8, sx/mbuf epilogue,
// 16B-chunk XOR swizzle (phys = logical ^ (row&7)) on the global source.
// MFMA 32x32x16 layouts: A: lane=A[row=l&31][k=8*(l>>5)+i];
// B: B[k=8*(l>>5)+i][col=l&31]; C/D: col=l&31, row=(reg&3)+8*(reg>>2)+4*(l>>5).
__global__ __launch_bounds__(512, 2) void attn_fwd(
    const float* __restrict__ Q, const short* __restrict__ Kbf,
    const short* __restrict__ Vtbf, float* __restrict__ O,
    float* __restrict__ Mo, float* __restrict__ Lo)
{
  __shared__ __align__(16) short smem[2*KVB*DD + 2*DD*KVB];  // 128KB: Kb | Vt
  __shared__ float sx[3][2][4][32];                          // m / tmax / lsum exchange

  short (*Kb)[KVB][DD] = reinterpret_cast<short(*)[KVB][DD]>(&smem[0]);
  short (*Vt)[DD][KVB] = reinterpret_cast<short(*)[DD][KVB]>(&smem[2*KVB*DD]);

  const int bid  = blockIdx.x;
  const int kvh  = bid & (NKV - 1);          // kvh == XCD id under round-robin
  const int q32  = 63 - (bid >> 3);          // heavies first, lights after: LPT queue
  const int wv   = threadIdx.x >> 6;         // 0..7
  const int headq= wv & 3;
  const int kh   = wv >> 2;                  // key half: keys [64kh, 64kh+64) per tile
  const int lane = threadIdx.x & 63;
  const int l31  = lane & 31;
  const int hiK  = lane >> 5;
  const int l7   = lane & 7;
  const int head = kvh * 4 + headq;
  const int qbase = q32 * 32;
  const int q    = qbase + l31;              // this lane's q-column

  // ---- staging offsets: wave stages K rows and V d-rows [16wv, 16wv+16) ----
  int koff[4], voff[4];
#pragma unroll
  for (int t = 0; t < 4; ++t) {
    const int row = 16 * wv + 4 * t + (lane >> 4);
    const int sw  = (lane & 15) ^ (4 * (t & 1) + (lane >> 4));
    koff[t] = row * DD + sw * 8;
    voff[t] = row * TT + sw * 8;
  }

  // ---- Q B-frags: lane holds Q[qbase+l31][ks*16 + 8*hiK + i], ks=0..7 ----
  short8 aq[8];
  {
    const float* qp = Q + ((size_t)q * NH + head) * DD + hiK * 8;
#pragma unroll
    for (int ks = 0; ks < 8; ++ks) {
      const float* p = qp + ks * 16;
      aq[ks] = cvt8(*reinterpret_cast<const f32x4*>(p),
                    *reinterpret_cast<const f32x4*>(p + 4));
    }
  }

  f32x16 acc[4];
#pragma unroll
  for (int i = 0; i < 4; ++i) acc[i] = (f32x16)0.0f;
  float m = -INFINITY, tmaxh = -INFINITY, lsum = 0.0f;

  const int ntiles = (q32 + 4) >> 2;   // ceil((qbase+32)/128)

  const short* kgp = Kbf + (size_t)kvh * TT * DD;
  const short* vgp = Vtbf + (size_t)kvh * DD * TT;

  // ---- prologue: DMA tile 0 into buffer 0 (K batch first, then V batch) ----
#pragma unroll
  for (int t = 0; t < 4; ++t)
    gload_lds16(kgp + koff[t], &Kb[0][16 * wv + 4 * t][0]);
#pragma unroll
  for (int t = 0; t < 4; ++t)
    gload_lds16(vgp + voff[t], &Vt[0][16 * wv + 4 * t][0]);
  kgp += (size_t)KVB * DD;
  vgp += KVB;

  for (int jt = 0; jt < ntiles; ++jt) {
    const int j0  = jt << 7;
    const int buf = jt & 1;

    // ---- barrier A: own K-DMA done (V's 4 still in flight); prev buffer free ----
    asm volatile("s_waitcnt vmcnt(4)" ::: "memory");
    __builtin_amdgcn_s_barrier();

    // ---- QK^T on this wave's 64-key half (reads Kb only; V lands under it) ----
    f32x16 st[2];
    st[0] = (f32x16)0.0f; st[1] = (f32x16)0.0f;
    __builtin_amdgcn_s_setprio(1);
#pragma unroll
    for (int kg = 0; kg < 2; ++kg) {
      const short* kr = &Kb[buf][kh * 64 + kg * 32 + l31][0];
#pragma unroll
      for (int ks = 0; ks < 8; ++ks) {
        const int c = ((ks << 1) | hiK) ^ l7;
        short8 kb = *reinterpret_cast<const short8*>(kr + c * 8);
        st[kg] = __builtin_amdgcn_mfma_f32_32x32x16_bf16(kb, aq[ks], st[kg], 0, 0, 0);
      }
    }
    __builtin_amdgcn_s_setprio(0);

    // ---- barrier B: all DMA drained -> Vt[buf] valid for every wave ----
    asm volatile("s_waitcnt vmcnt(0)" ::: "memory");
    __builtin_amdgcn_s_barrier();

    // ---- DMA tile jt+1 into buf^1 (AFTER barrier B so vmcnt(0) didn't drain it) ----
    if (jt + 1 < ntiles) {
      const int nb = buf ^ 1;
#pragma unroll
      for (int t = 0; t < 4; ++t)
        gload_lds16(kgp + koff[t], &Kb[nb][16 * wv + 4 * t][0]);
#pragma unroll
      for (int t = 0; t < 4; ++t)
        gload_lds16(vgp + voff[t], &Vt[nb][16 * wv + 4 * t][0]);
      kgp += (size_t)KVB * DD;
      vgp += KVB;
    }

    // ---- causal mask: only the last tile can cross the diagonal ----
    if (jt == ntiles - 1) {
#pragma unroll
      for (int kg = 0; kg < 2; ++kg)
#pragma unroll
        for (int r = 0; r < 16; ++r) {
          const int key = j0 + kh * 64 + kg * 32 + (r & 3) + 8 * (r >> 2) + 4 * hiK;
          if (key > q) st[kg][r] = -1.0e10f;
        }
    }

    // ---- half max (lane-local over 64 keys + lane^32 merge) ----
    float mx = fmaxf(st[0][0], st[1][0]);
#pragma unroll
    for (int r = 1; r < 16; ++r) mx = fmaxf(mx, fmaxf(st[0][r], st[1][r]));
    mx = fmaxf(mx, __shfl_xor(mx, 32, 64));
    tmaxh = fmaxf(tmaxh, mx);

    // ---- defer-max: rescale only when the running max grows by >THR ----
    if (__any(mx > m + THR)) {
      const float mn = fmaxf(m, mx);
      const float sc = __expf(m - mn);
      m = mn;
      lsum *= sc;
#pragma unroll
      for (int r = 0; r < 16; ++r) {
        const float sf = __shfl(sc, (r & 3) + 8 * (r >> 2) + 4 * hiK, 64);
        acc[0][r] *= sf; acc[1][r] *= sf; acc[2][r] *= sf; acc[3][r] *= sf;
      }
    }

    // ---- P = exp(S-m); pack to PV A-frags via lane^32 exchange ----
    short8 pa[4];
#pragma unroll
    for (int kg = 0; kg < 2; ++kg) {
      float e[16];
#pragma unroll
      for (int r = 0; r < 16; ++r) e[r] = __expf(st[kg][r] - m);
      lsum += (((e[0]+e[1])+(e[2]+e[3]))+((e[4]+e[5])+(e[6]+e[7])))
            + (((e[8]+e[9])+(e[10]+e[11]))+((e[12]+e[13])+(e[14]+e[15])));
#pragma unroll
      for (int h2 = 0; h2 < 2; ++h2) {
        const int b = 8 * h2;
        u32 u0 = pk2(e[b+0], e[b+1]);
        u32 u1 = pk2(e[b+2], e[b+3]);
        u32 u2 = pk2(e[b+4], e[b+5]);
        u32 u3 = pk2(e[b+6], e[b+7]);
        u32 sA = hiK ? u0 : u2;
        u32 sB = hiK ? u1 : u3;
        u32 rA = __shfl_xor(sA, 32, 64);
        u32 rB = __shfl_xor(sB, 32, 64);
        u32x4 w4;
        w4[0] = hiK ? rA : u0;
        w4[1] = hiK ? rB : u1;
        w4[2] = hiK ? u2 : rA;
        w4[3] = hiK ? u3 : rB;
        pa[kg * 2 + h2] = __builtin_bit_cast(short8, w4);
      }
    }

    // ---- P @ V over this wave's 4 key-slices of 16 (keys kh*64 + 16pi) ----
    __builtin_amdgcn_s_setprio(1);
#pragma unroll
    for (int dg = 0; dg < 4; ++dg) {
      const short* vr = &Vt[buf][dg * 32 + l31][0];
#pragma unroll
      for (int pi = 0; pi < 4; ++pi) {
        const int c = (8 * kh + 2 * pi + hiK) ^ l7;
        short8 vb = *reinterpret_cast<const short8*>(vr + c * 8);
        acc[dg] = __builtin_amdgcn_mfma_f32_32x32x16_bf16(pa[pi], vb, acc[dg], 0, 0, 0);
      }
    }
    __builtin_amdgcn_s_setprio(0);
  }

  // ---- epilogue: merge the two key-halves (r14 verbatim; full __syncthreads) ----
  const float lw = lsum + __shfl_xor(lsum, 32, 64);
  __syncthreads();                     // all PV done; K/V LDS is dead now
  if (lane < 32) {
    sx[0][kh][headq][lane] = m;
    sx[1][kh][headq][lane] = tmaxh;
    sx[2][kh][headq][lane] = lw;
  }
  __syncthreads();
  const float mo   = sx[0][kh ^ 1][headq][l31];
  const float to   = sx[1][kh ^ 1][headq][l31];
  const float lo2  = sx[2][kh ^ 1][headq][l31];
  const float tmax = fmaxf(tmaxh, to);
  const float fsA  = __expf(m - tmax);          // own-half scale to true max
  const float ltot = lw * fsA + lo2 * __expf(mo - tmax);

  float* mbuf = reinterpret_cast<float*>(&smem[0]);   // 64KB = 4 heads x 32q x 128d
  if (kh == 1) {
#pragma unroll
    for (int r = 0; r < 16; ++r) {
      const int row = (r & 3) + 8 * (r >> 2) + 4 * hiK;
      const float sfr = __shfl(fsA, row, 64);
#pragma unroll
      for (int dg = 0; dg < 4; ++dg)
        mbuf[headq * 4096 + row * 128 + dg * 32 + l31] = acc[dg][r] * sfr;
    }
  }
  __syncthreads();
  if (kh == 0) {
#pragma unroll
    for (int r = 0; r < 16; ++r) {
      const int row = (r & 3) + 8 * (r >> 2) + 4 * hiK;
      const float sfr = __shfl(fsA, row, 64);
      const size_t ob = ((size_t)(qbase + row) * NH + head) * DD + l31;
#pragma unroll
      for (int dg = 0; dg < 4; ++dg)
        O[ob + dg * 32] = acc[dg][r] * sfr + mbuf[headq * 4096 + row * 128 + dg * 32 + l31];
    }
    if (lane < 32) {
      Mo[(size_t)q * NH + head] = tmax;
      Lo[(size_t)q * NH + head] = ltot;
    }
  }
}

extern "C" void kernel_launch(void* const* d_in, const int* in_sizes, int n_in,
                              void* d_out, int out_size, void* d_ws, size_t ws_size,
                              hipStream_t stream) {
  const float* Q = (const float*)d_in[0];
  const float* K = (const float*)d_in[1];
  const float* V = (const float*)d_in[2];
  float* O  = (float*)d_out;
  float* Mo = O + (size_t)TT * NH * DD;
  float* Lo = Mo + (size_t)TT * NH;
  short* Kbf  = (short*)d_ws;                          // 4 MB
  short* Vtbf = Kbf + (size_t)NKV * TT * DD;           // 4 MB
  preconv<<<dim3(512), dim3(256), 0, stream>>>(K, V, Kbf, Vtbf);
  attn_fwd<<<dim3(64 * NKV), dim3(512), 0, stream>>>(Q, Kbf, Vtbf, O, Mo, Lo);
}

// Round 19
// 77.637 us; speedup vs baseline: 1.0407x; 1.0407x over previous
//
#include <hip/hip_runtime.h>
#include <hip/hip_bf16.h>

#define TT  2048
#define NH  32
#define NKV 8
#define DD  128
#define KVB 128         // keys per LDS tile (halves barrier count vs 64)
#define THR 8.0f        // defer-max rescale threshold (T13)

typedef __attribute__((ext_vector_type(8)))  short  short8;
typedef __attribute__((ext_vector_type(4)))  float  f32x4;
typedef __attribute__((ext_vector_type(16))) float  f32x16;
typedef unsigned int u32;
typedef __attribute__((ext_vector_type(4)))  u32    u32x4;

static __device__ __forceinline__ short f2bf(float x) {
  __bf16 b = (__bf16)x;                 // RNE f32->bf16
  return __builtin_bit_cast(short, b);
}
static __device__ __forceinline__ short8 cvt8(f32x4 a, f32x4 b) {
  short8 r;
  r[0]=f2bf(a[0]); r[1]=f2bf(a[1]); r[2]=f2bf(a[2]); r[3]=f2bf(a[3]);
  r[4]=f2bf(b[0]); r[5]=f2bf(b[1]); r[6]=f2bf(b[2]); r[7]=f2bf(b[3]);
  return r;
}
static __device__ __forceinline__ u32 pk2(float lo, float hi) {
  const u32 a = (u32)(unsigned short)f2bf(lo);
  const u32 b = (u32)(unsigned short)f2bf(hi);
  return a | (b << 16);
}
static __device__ __forceinline__ void gload_lds16(const short* g, short* l) {
  __builtin_amdgcn_global_load_lds(
      (const __attribute__((address_space(1))) u32*)g,
      (__attribute__((address_space(3))) u32*)l, 16, 0, 0);
}

// ---------------- pre-pass: K -> bf16 [kvh][j][d]; V -> bf16 transposed [kvh][d][j] ----
__global__ __launch_bounds__(256) void preconv(
    const float* __restrict__ K, const float* __restrict__ V,
    short* __restrict__ Kbf, short* __restrict__ Vtbf)
{
  const int t = threadIdx.x;
  if (blockIdx.x >= 256) {
    const int b  = blockIdx.x - 256;
    const int rr = (b << 6) + (t >> 2);      // rr = j*8+kvh
    const int q  = t & 3;
    const int j = rr >> 3, kvh = rr & 7;
    const float* src = K + (size_t)rr * DD + q * 32;
    short* dst = Kbf + ((size_t)kvh * TT + j) * DD + q * 32;
#pragma unroll
    for (int i = 0; i < 4; ++i) {
      f32x4 a  = *reinterpret_cast<const f32x4*>(src + i * 8);
      f32x4 bb = *reinterpret_cast<const f32x4*>(src + i * 8 + 4);
      *reinterpret_cast<short8*>(dst + i * 8) = cvt8(a, bb);
    }
  } else {
    const int kvh = blockIdx.x >> 5, jt = blockIdx.x & 31;
    __shared__ short Vl[64][136];
    const int jl = t >> 2, q = t & 3;
    const float* src = V + ((size_t)(jt * 64 + jl) * NKV + kvh) * DD + q * 32;
#pragma unroll
    for (int i = 0; i < 4; ++i) {
      f32x4 a  = *reinterpret_cast<const f32x4*>(src + i * 8);
      f32x4 bb = *reinterpret_cast<const f32x4*>(src + i * 8 + 4);
      *reinterpret_cast<short8*>(&Vl[jl][q * 32 + i * 8]) = cvt8(a, bb);
    }
    __syncthreads();
    const int d = t >> 1, jh = t & 1;
    short8 o[4];
#pragma unroll
    for (int k = 0; k < 4; ++k)
#pragma unroll
      for (int i = 0; i < 8; ++i)
        o[k][i] = Vl[jh * 32 + k * 8 + i][d];
    short* dst = Vtbf + ((size_t)kvh * DD + d) * TT + jt * 64 + jh * 32;
#pragma unroll
    for (int k = 0; k < 4; ++k)
      *reinterpret_cast<short8*>(dst + k * 8) = o[k];
  }
}

// ---------------- main attention kernel ------------------------------------------
// SESSION-FINAL: the round-14 kernel verbatim (measured 77.6us, re-verified 77.55us
// at r17 -- best of session; entry baseline was 152.0us => 1.96x).
// Structure: KVB=128 (halves per-strip barrier/drain count vs 64), 8 waves =
// 4 GQA heads x 2 key-halves with independent per-half online softmax and
// defer-max THR=8; DMA issued AFTER QK^T (r13: before-QK^T contends with QK's
// ds_reads, -6%); single __syncthreads per tile (r18: counted-vmcnt split drain
// adds a barrier and regresses -4%); sx/mbuf LDS epilogue merge; grid order
// heavies-descending-then-lights = LPT queue under greedy backfill (r10/r15/r16:
// explicit balancing ties at best, spills at worst). K/V double-buffered, staged
// by global_load_lds with the 16B-chunk XOR swizzle (phys = logical ^ (row&7))
// pre-applied on the per-lane GLOBAL source address (LDS dest linear, rule 21).
// Remaining gap to hardware (MfmaUtil 19%, HBM 9%) is latency at 2 waves/SIMD:
// 176 unified regs/wave blocks 4 waves/SIMD without halving the 64-reg
// accumulator (= output-ownership redesign; out of session scope).
// MFMA 32x32x16 layouts: A: lane=A[row=l&31][k=8*(l>>5)+i];
// B: B[k=8*(l>>5)+i][col=l&31]; C/D: col=l&31, row=(reg&3)+8*(reg>>2)+4*(l>>5).
__global__ __launch_bounds__(512, 2) void attn_fwd(
    const float* __restrict__ Q, const short* __restrict__ Kbf,
    const short* __restrict__ Vtbf, float* __restrict__ O,
    float* __restrict__ Mo, float* __restrict__ Lo)
{
  __shared__ __align__(16) short smem[2*KVB*DD + 2*DD*KVB];  // 128KB: Kb | Vt
  __shared__ float sx[3][2][4][32];                          // m / tmax / lsum exchange

  short (*Kb)[KVB][DD] = reinterpret_cast<short(*)[KVB][DD]>(&smem[0]);
  short (*Vt)[DD][KVB] = reinterpret_cast<short(*)[DD][KVB]>(&smem[2*KVB*DD]);

  const int bid  = blockIdx.x;
  const int kvh  = bid & (NKV - 1);          // kvh == XCD id under round-robin
  const int q32  = 63 - (bid >> 3);          // heavies first, lights after: LPT queue
  const int wv   = threadIdx.x >> 6;         // 0..7
  const int headq= wv & 3;
  const int kh   = wv >> 2;                  // key half: keys [64kh, 64kh+64) per tile
  const int lane = threadIdx.x & 63;
  const int l31  = lane & 31;
  const int hiK  = lane >> 5;
  const int l7   = lane & 7;
  const int head = kvh * 4 + headq;
  const int qbase = q32 * 32;
  const int q    = qbase + l31;              // this lane's q-column

  // ---- staging offsets: wave stages K rows and V d-rows [16wv, 16wv+16) ----
  int koff[4], voff[4];
#pragma unroll
  for (int t = 0; t < 4; ++t) {
    const int row = 16 * wv + 4 * t + (lane >> 4);
    const int sw  = (lane & 15) ^ (4 * (t & 1) + (lane >> 4));
    koff[t] = row * DD + sw * 8;
    voff[t] = row * TT + sw * 8;
  }

  // ---- Q B-frags: lane holds Q[qbase+l31][ks*16 + 8*hiK + i], ks=0..7 ----
  short8 aq[8];
  {
    const float* qp = Q + ((size_t)q * NH + head) * DD + hiK * 8;
#pragma unroll
    for (int ks = 0; ks < 8; ++ks) {
      const float* p = qp + ks * 16;
      aq[ks] = cvt8(*reinterpret_cast<const f32x4*>(p),
                    *reinterpret_cast<const f32x4*>(p + 4));
    }
  }

  f32x16 acc[4];
#pragma unroll
  for (int i = 0; i < 4; ++i) acc[i] = (f32x16)0.0f;
  float m = -INFINITY, tmaxh = -INFINITY, lsum = 0.0f;

  const int ntiles = (q32 + 4) >> 2;   // ceil((qbase+32)/128)

  const short* kgp = Kbf + (size_t)kvh * TT * DD;
  const short* vgp = Vtbf + (size_t)kvh * DD * TT;

  // ---- prologue: DMA tile 0 into buffer 0 ----
#pragma unroll
  for (int t = 0; t < 4; ++t)
    gload_lds16(kgp + koff[t], &Kb[0][16 * wv + 4 * t][0]);
#pragma unroll
  for (int t = 0; t < 4; ++t)
    gload_lds16(vgp + voff[t], &Vt[0][16 * wv + 4 * t][0]);
  kgp += (size_t)KVB * DD;
  vgp += KVB;

  for (int jt = 0; jt < ntiles; ++jt) {
    const int j0  = jt << 7;
    const int buf = jt & 1;

    __syncthreads();   // drains own DMA (vmcnt0); prev buffer free for overwrite

    // ---- QK^T on this wave's 64-key half: st[kg] over keys kh*64+kg*32+[0,32) ----
    f32x16 st[2];
    st[0] = (f32x16)0.0f; st[1] = (f32x16)0.0f;
    __builtin_amdgcn_s_setprio(1);
#pragma unroll
    for (int kg = 0; kg < 2; ++kg) {
      const short* kr = &Kb[buf][kh * 64 + kg * 32 + l31][0];
#pragma unroll
      for (int ks = 0; ks < 8; ++ks) {
        const int c = ((ks << 1) | hiK) ^ l7;
        short8 kb = *reinterpret_cast<const short8*>(kr + c * 8);
        st[kg] = __builtin_amdgcn_mfma_f32_32x32x16_bf16(kb, aq[ks], st[kg], 0, 0, 0);
      }
    }
    __builtin_amdgcn_s_setprio(0);

    // ---- DMA tile jt+1 into buf^1 (r7/r13-proven placement: after QK^T) ----
    if (jt + 1 < ntiles) {
      const int nb = buf ^ 1;
#pragma unroll
      for (int t = 0; t < 4; ++t)
        gload_lds16(kgp + koff[t], &Kb[nb][16 * wv + 4 * t][0]);
#pragma unroll
      for (int t = 0; t < 4; ++t)
        gload_lds16(vgp + voff[t], &Vt[nb][16 * wv + 4 * t][0]);
      kgp += (size_t)KVB * DD;
      vgp += KVB;
    }

    // ---- causal mask: only the last tile can cross the diagonal ----
    if (jt == ntiles - 1) {
#pragma unroll
      for (int kg = 0; kg < 2; ++kg)
#pragma unroll
        for (int r = 0; r < 16; ++r) {
          const int key = j0 + kh * 64 + kg * 32 + (r & 3) + 8 * (r >> 2) + 4 * hiK;
          if (key > q) st[kg][r] = -1.0e10f;
        }
    }

    // ---- half max (lane-local over 64 keys + lane^32 merge) ----
    float mx = fmaxf(st[0][0], st[1][0]);
#pragma unroll
    for (int r = 1; r < 16; ++r) mx = fmaxf(mx, fmaxf(st[0][r], st[1][r]));
    mx = fmaxf(mx, __shfl_xor(mx, 32, 64));
    tmaxh = fmaxf(tmaxh, mx);

    // ---- defer-max: rescale only when the running max grows by >THR ----
    if (__any(mx > m + THR)) {
      const float mn = fmaxf(m, mx);
      const float sc = __expf(m - mn);
      m = mn;
      lsum *= sc;
#pragma unroll
      for (int r = 0; r < 16; ++r) {
        const float sf = __shfl(sc, (r & 3) + 8 * (r >> 2) + 4 * hiK, 64);
        acc[0][r] *= sf; acc[1][r] *= sf; acc[2][r] *= sf; acc[3][r] *= sf;
      }
    }

    // ---- P = exp(S-m); pack to PV A-frags via lane^32 exchange ----
    short8 pa[4];
#pragma unroll
    for (int kg = 0; kg < 2; ++kg) {
      float e[16];
#pragma unroll
      for (int r = 0; r < 16; ++r) e[r] = __expf(st[kg][r] - m);
      lsum += (((e[0]+e[1])+(e[2]+e[3]))+((e[4]+e[5])+(e[6]+e[7])))
            + (((e[8]+e[9])+(e[10]+e[11]))+((e[12]+e[13])+(e[14]+e[15])));
#pragma unroll
      for (int h2 = 0; h2 < 2; ++h2) {
        const int b = 8 * h2;
        u32 u0 = pk2(e[b+0], e[b+1]);
        u32 u1 = pk2(e[b+2], e[b+3]);
        u32 u2 = pk2(e[b+4], e[b+5]);
        u32 u3 = pk2(e[b+6], e[b+7]);
        u32 sA = hiK ? u0 : u2;
        u32 sB = hiK ? u1 : u3;
        u32 rA = __shfl_xor(sA, 32, 64);
        u32 rB = __shfl_xor(sB, 32, 64);
        u32x4 w4;
        w4[0] = hiK ? rA : u0;
        w4[1] = hiK ? rB : u1;
        w4[2] = hiK ? u2 : rA;
        w4[3] = hiK ? u3 : rB;
        pa[kg * 2 + h2] = __builtin_bit_cast(short8, w4);
      }
    }

    // ---- P @ V over this wave's 4 key-slices of 16 (keys kh*64 + 16pi) ----
    __builtin_amdgcn_s_setprio(1);
#pragma unroll
    for (int dg = 0; dg < 4; ++dg) {
      const short* vr = &Vt[buf][dg * 32 + l31][0];
#pragma unroll
      for (int pi = 0; pi < 4; ++pi) {
        const int c = (8 * kh + 2 * pi + hiK) ^ l7;
        short8 vb = *reinterpret_cast<const short8*>(vr + c * 8);
        acc[dg] = __builtin_amdgcn_mfma_f32_32x32x16_bf16(pa[pi], vb, acc[dg], 0, 0, 0);
      }
    }
    __builtin_amdgcn_s_setprio(0);
  }

  // ---- epilogue: merge the two key-halves ----
  const float lw = lsum + __shfl_xor(lsum, 32, 64);
  __syncthreads();                     // all PV done; K/V LDS is dead now
  if (lane < 32) {
    sx[0][kh][headq][lane] = m;
    sx[1][kh][headq][lane] = tmaxh;
    sx[2][kh][headq][lane] = lw;
  }
  __syncthreads();
  const float mo   = sx[0][kh ^ 1][headq][l31];
  const float to   = sx[1][kh ^ 1][headq][l31];
  const float lo2  = sx[2][kh ^ 1][headq][l31];
  const float tmax = fmaxf(tmaxh, to);
  const float fsA  = __expf(m - tmax);          // own-half scale to true max
  const float ltot = lw * fsA + lo2 * __expf(mo - tmax);

  float* mbuf = reinterpret_cast<float*>(&smem[0]);   // 64KB = 4 heads x 32q x 128d
  if (kh == 1) {
#pragma unroll
    for (int r = 0; r < 16; ++r) {
      const int row = (r & 3) + 8 * (r >> 2) + 4 * hiK;
      const float sfr = __shfl(fsA, row, 64);
#pragma unroll
      for (int dg = 0; dg < 4; ++dg)
        mbuf[headq * 4096 + row * 128 + dg * 32 + l31] = acc[dg][r] * sfr;
    }
  }
  __syncthreads();
  if (kh == 0) {
#pragma unroll
    for (int r = 0; r < 16; ++r) {
      const int row = (r & 3) + 8 * (r >> 2) + 4 * hiK;
      const float sfr = __shfl(fsA, row, 64);
      const size_t ob = ((size_t)(qbase + row) * NH + head) * DD + l31;
#pragma unroll
      for (int dg = 0; dg < 4; ++dg)
        O[ob + dg * 32] = acc[dg][r] * sfr + mbuf[headq * 4096 + row * 128 + dg * 32 + l31];
    }
    if (lane < 32) {
      Mo[(size_t)q * NH + head] = tmax;
      Lo[(size_t)q * NH + head] = ltot;
    }
  }
}

extern "C" void kernel_launch(void* const* d_in, const int* in_sizes, int n_in,
                              void* d_out, int out_size, void* d_ws, size_t ws_size,
                              hipStream_t stream) {
  const float* Q = (const float*)d_in[0];
  const float* K = (const float*)d_in[1];
  const float* V = (const float*)d_in[2];
  float* O  = (float*)d_out;
  float* Mo = O + (size_t)TT * NH * DD;
  float* Lo = Mo + (size_t)TT * NH;
  short* Kbf  = (short*)d_ws;                          // 4 MB
  short* Vtbf = Kbf + (size_t)NKV * TT * DD;           // 4 MB
  preconv<<<dim3(512), dim3(256), 0, stream>>>(K, V, Kbf, Vtbf);
  attn_fwd<<<dim3(64 * NKV), dim3(512), 0, stream>>>(Q, Kbf, Vtbf, O, Mo, Lo);
}

// Round 20
// 77.286 us; speedup vs baseline: 1.0454x; 1.0045x over previous
//
#include <hip/hip_runtime.h>
#include <hip/hip_bf16.h>

#define TT  2048
#define NH  32
#define NKV 8
#define DD  128
#define KVB 128         // keys per LDS tile (halves barrier count vs 64)
#define THR 8.0f        // defer-max rescale threshold (T13)

typedef __attribute__((ext_vector_type(8)))  short  short8;
typedef __attribute__((ext_vector_type(4)))  float  f32x4;
typedef __attribute__((ext_vector_type(16))) float  f32x16;
typedef unsigned int u32;
typedef __attribute__((ext_vector_type(4)))  u32    u32x4;

static __device__ __forceinline__ short f2bf(float x) {
  __bf16 b = (__bf16)x;                 // RNE f32->bf16
  return __builtin_bit_cast(short, b);
}
static __device__ __forceinline__ short8 cvt8(f32x4 a, f32x4 b) {
  short8 r;
  r[0]=f2bf(a[0]); r[1]=f2bf(a[1]); r[2]=f2bf(a[2]); r[3]=f2bf(a[3]);
  r[4]=f2bf(b[0]); r[5]=f2bf(b[1]); r[6]=f2bf(b[2]); r[7]=f2bf(b[3]);
  return r;
}
static __device__ __forceinline__ u32 pk2(float lo, float hi) {
  const u32 a = (u32)(unsigned short)f2bf(lo);
  const u32 b = (u32)(unsigned short)f2bf(hi);
  return a | (b << 16);
}
static __device__ __forceinline__ void gload_lds16(const short* g, short* l) {
  __builtin_amdgcn_global_load_lds(
      (const __attribute__((address_space(1))) u32*)g,
      (__attribute__((address_space(3))) u32*)l, 16, 0, 0);
}

// ---------------- pre-pass: K -> bf16 [kvh][j][d]; V -> bf16 transposed [kvh][d][j] ----
__global__ __launch_bounds__(256) void preconv(
    const float* __restrict__ K, const float* __restrict__ V,
    short* __restrict__ Kbf, short* __restrict__ Vtbf)
{
  const int t = threadIdx.x;
  if (blockIdx.x >= 256) {
    const int b  = blockIdx.x - 256;
    const int rr = (b << 6) + (t >> 2);      // rr = j*8+kvh
    const int q  = t & 3;
    const int j = rr >> 3, kvh = rr & 7;
    const float* src = K + (size_t)rr * DD + q * 32;
    short* dst = Kbf + ((size_t)kvh * TT + j) * DD + q * 32;
#pragma unroll
    for (int i = 0; i < 4; ++i) {
      f32x4 a  = *reinterpret_cast<const f32x4*>(src + i * 8);
      f32x4 bb = *reinterpret_cast<const f32x4*>(src + i * 8 + 4);
      *reinterpret_cast<short8*>(dst + i * 8) = cvt8(a, bb);
    }
  } else {
    const int kvh = blockIdx.x >> 5, jt = blockIdx.x & 31;
    __shared__ short Vl[64][136];
    const int jl = t >> 2, q = t & 3;
    const float* src = V + ((size_t)(jt * 64 + jl) * NKV + kvh) * DD + q * 32;
#pragma unroll
    for (int i = 0; i < 4; ++i) {
      f32x4 a  = *reinterpret_cast<const f32x4*>(src + i * 8);
      f32x4 bb = *reinterpret_cast<const f32x4*>(src + i * 8 + 4);
      *reinterpret_cast<short8*>(&Vl[jl][q * 32 + i * 8]) = cvt8(a, bb);
    }
    __syncthreads();
    const int d = t >> 1, jh = t & 1;
    short8 o[4];
#pragma unroll
    for (int k = 0; k < 4; ++k)
#pragma unroll
      for (int i = 0; i < 8; ++i)
        o[k][i] = Vl[jh * 32 + k * 8 + i][d];
    short* dst = Vtbf + ((size_t)kvh * DD + d) * TT + jt * 64 + jh * 32;
#pragma unroll
    for (int k = 0; k < 4; ++k)
      *reinterpret_cast<short8*>(dst + k * 8) = o[k];
  }
}

// ---------------- main attention kernel ------------------------------------------
// r14 body (proven 77.6us, reproduced r17/r19) with ONE change: s_setprio REMOVED.
// T5 mechanism check: setprio pays only with wave role-diversity on a SIMD
// (m191: +4-7% on independent 1-wave attn blocks); on barrier-LOCKSTEPPED
// structures it is null-to-negative (m190: 4-wave lockstep GEMM, -1.5%). This
// kernel is the lockstep case -- all 8 waves hit the same __syncthreads every
// tile, so both waves/SIMD want MFMA simultaneously; prio=1 through the MFMA
// clusters only delays the co-resident wave's softmax. The calls were inherited
// from the r6-era independent-block structure and never re-validated.
// Everything else r14-verbatim: KVB=128, 8 waves = 4 GQA heads x 2 key-halves,
// independent per-half online softmax with defer-max THR=8, DMA issued AFTER
// QK^T (r13: before is -6%), single __syncthreads per tile (r18: split drain
// is -4%), sx/mbuf LDS epilogue merge, heavies-first grid order (LPT under
// greedy backfill), K/V dbuf staged by global_load_lds with the 16B-chunk XOR
// swizzle (phys = logical ^ (row&7)) pre-applied on the global source address.
// MFMA 32x32x16 layouts: A: lane=A[row=l&31][k=8*(l>>5)+i];
// B: B[k=8*(l>>5)+i][col=l&31]; C/D: col=l&31, row=(reg&3)+8*(reg>>2)+4*(l>>5).
__global__ __launch_bounds__(512, 2) void attn_fwd(
    const float* __restrict__ Q, const short* __restrict__ Kbf,
    const short* __restrict__ Vtbf, float* __restrict__ O,
    float* __restrict__ Mo, float* __restrict__ Lo)
{
  __shared__ __align__(16) short smem[2*KVB*DD + 2*DD*KVB];  // 128KB: Kb | Vt
  __shared__ float sx[3][2][4][32];                          // m / tmax / lsum exchange

  short (*Kb)[KVB][DD] = reinterpret_cast<short(*)[KVB][DD]>(&smem[0]);
  short (*Vt)[DD][KVB] = reinterpret_cast<short(*)[DD][KVB]>(&smem[2*KVB*DD]);

  const int bid  = blockIdx.x;
  const int kvh  = bid & (NKV - 1);          // kvh == XCD id under round-robin
  const int q32  = 63 - (bid >> 3);          // heavies first, lights after: LPT queue
  const int wv   = threadIdx.x >> 6;         // 0..7
  const int headq= wv & 3;
  const int kh   = wv >> 2;                  // key half: keys [64kh, 64kh+64) per tile
  const int lane = threadIdx.x & 63;
  const int l31  = lane & 31;
  const int hiK  = lane >> 5;
  const int l7   = lane & 7;
  const int head = kvh * 4 + headq;
  const int qbase = q32 * 32;
  const int q    = qbase + l31;              // this lane's q-column

  // ---- staging offsets: wave stages K rows and V d-rows [16wv, 16wv+16) ----
  int koff[4], voff[4];
#pragma unroll
  for (int t = 0; t < 4; ++t) {
    const int row = 16 * wv + 4 * t + (lane >> 4);
    const int sw  = (lane & 15) ^ (4 * (t & 1) + (lane >> 4));
    koff[t] = row * DD + sw * 8;
    voff[t] = row * TT + sw * 8;
  }

  // ---- Q B-frags: lane holds Q[qbase+l31][ks*16 + 8*hiK + i], ks=0..7 ----
  short8 aq[8];
  {
    const float* qp = Q + ((size_t)q * NH + head) * DD + hiK * 8;
#pragma unroll
    for (int ks = 0; ks < 8; ++ks) {
      const float* p = qp + ks * 16;
      aq[ks] = cvt8(*reinterpret_cast<const f32x4*>(p),
                    *reinterpret_cast<const f32x4*>(p + 4));
    }
  }

  f32x16 acc[4];
#pragma unroll
  for (int i = 0; i < 4; ++i) acc[i] = (f32x16)0.0f;
  float m = -INFINITY, tmaxh = -INFINITY, lsum = 0.0f;

  const int ntiles = (q32 + 4) >> 2;   // ceil((qbase+32)/128)

  const short* kgp = Kbf + (size_t)kvh * TT * DD;
  const short* vgp = Vtbf + (size_t)kvh * DD * TT;

  // ---- prologue: DMA tile 0 into buffer 0 ----
#pragma unroll
  for (int t = 0; t < 4; ++t)
    gload_lds16(kgp + koff[t], &Kb[0][16 * wv + 4 * t][0]);
#pragma unroll
  for (int t = 0; t < 4; ++t)
    gload_lds16(vgp + voff[t], &Vt[0][16 * wv + 4 * t][0]);
  kgp += (size_t)KVB * DD;
  vgp += KVB;

  for (int jt = 0; jt < ntiles; ++jt) {
    const int j0  = jt << 7;
    const int buf = jt & 1;

    __syncthreads();   // drains own DMA (vmcnt0); prev buffer free for overwrite

    // ---- QK^T on this wave's 64-key half: st[kg] over keys kh*64+kg*32+[0,32) ----
    f32x16 st[2];
    st[0] = (f32x16)0.0f; st[1] = (f32x16)0.0f;
#pragma unroll
    for (int kg = 0; kg < 2; ++kg) {
      const short* kr = &Kb[buf][kh * 64 + kg * 32 + l31][0];
#pragma unroll
      for (int ks = 0; ks < 8; ++ks) {
        const int c = ((ks << 1) | hiK) ^ l7;
        short8 kb = *reinterpret_cast<const short8*>(kr + c * 8);
        st[kg] = __builtin_amdgcn_mfma_f32_32x32x16_bf16(kb, aq[ks], st[kg], 0, 0, 0);
      }
    }

    // ---- DMA tile jt+1 into buf^1 (r7/r13-proven placement: after QK^T) ----
    if (jt + 1 < ntiles) {
      const int nb = buf ^ 1;
#pragma unroll
      for (int t = 0; t < 4; ++t)
        gload_lds16(kgp + koff[t], &Kb[nb][16 * wv + 4 * t][0]);
#pragma unroll
      for (int t = 0; t < 4; ++t)
        gload_lds16(vgp + voff[t], &Vt[nb][16 * wv + 4 * t][0]);
      kgp += (size_t)KVB * DD;
      vgp += KVB;
    }

    // ---- causal mask: only the last tile can cross the diagonal ----
    if (jt == ntiles - 1) {
#pragma unroll
      for (int kg = 0; kg < 2; ++kg)
#pragma unroll
        for (int r = 0; r < 16; ++r) {
          const int key = j0 + kh * 64 + kg * 32 + (r & 3) + 8 * (r >> 2) + 4 * hiK;
          if (key > q) st[kg][r] = -1.0e10f;
        }
    }

    // ---- half max (lane-local over 64 keys + lane^32 merge) ----
    float mx = fmaxf(st[0][0], st[1][0]);
#pragma unroll
    for (int r = 1; r < 16; ++r) mx = fmaxf(mx, fmaxf(st[0][r], st[1][r]));
    mx = fmaxf(mx, __shfl_xor(mx, 32, 64));
    tmaxh = fmaxf(tmaxh, mx);

    // ---- defer-max: rescale only when the running max grows by >THR ----
    if (__any(mx > m + THR)) {
      const float mn = fmaxf(m, mx);
      const float sc = __expf(m - mn);
      m = mn;
      lsum *= sc;
#pragma unroll
      for (int r = 0; r < 16; ++r) {
        const float sf = __shfl(sc, (r & 3) + 8 * (r >> 2) + 4 * hiK, 64);
        acc[0][r] *= sf; acc[1][r] *= sf; acc[2][r] *= sf; acc[3][r] *= sf;
      }
    }

    // ---- P = exp(S-m); pack to PV A-frags via lane^32 exchange ----
    short8 pa[4];
#pragma unroll
    for (int kg = 0; kg < 2; ++kg) {
      float e[16];
#pragma unroll
      for (int r = 0; r < 16; ++r) e[r] = __expf(st[kg][r] - m);
      lsum += (((e[0]+e[1])+(e[2]+e[3]))+((e[4]+e[5])+(e[6]+e[7])))
            + (((e[8]+e[9])+(e[10]+e[11]))+((e[12]+e[13])+(e[14]+e[15])));
#pragma unroll
      for (int h2 = 0; h2 < 2; ++h2) {
        const int b = 8 * h2;
        u32 u0 = pk2(e[b+0], e[b+1]);
        u32 u1 = pk2(e[b+2], e[b+3]);
        u32 u2 = pk2(e[b+4], e[b+5]);
        u32 u3 = pk2(e[b+6], e[b+7]);
        u32 sA = hiK ? u0 : u2;
        u32 sB = hiK ? u1 : u3;
        u32 rA = __shfl_xor(sA, 32, 64);
        u32 rB = __shfl_xor(sB, 32, 64);
        u32x4 w4;
        w4[0] = hiK ? rA : u0;
        w4[1] = hiK ? rB : u1;
        w4[2] = hiK ? u2 : rA;
        w4[3] = hiK ? u3 : rB;
        pa[kg * 2 + h2] = __builtin_bit_cast(short8, w4);
      }
    }

    // ---- P @ V over this wave's 4 key-slices of 16 (keys kh*64 + 16pi) ----
#pragma unroll
    for (int dg = 0; dg < 4; ++dg) {
      const short* vr = &Vt[buf][dg * 32 + l31][0];
#pragma unroll
      for (int pi = 0; pi < 4; ++pi) {
        const int c = (8 * kh + 2 * pi + hiK) ^ l7;
        short8 vb = *reinterpret_cast<const short8*>(vr + c * 8);
        acc[dg] = __builtin_amdgcn_mfma_f32_32x32x16_bf16(pa[pi], vb, acc[dg], 0, 0, 0);
      }
    }
  }

  // ---- epilogue: merge the two key-halves ----
  const float lw = lsum + __shfl_xor(lsum, 32, 64);
  __syncthreads();                     // all PV done; K/V LDS is dead now
  if (lane < 32) {
    sx[0][kh][headq][lane] = m;
    sx[1][kh][headq][lane] = tmaxh;
    sx[2][kh][headq][lane] = lw;
  }
  __syncthreads();
  const float mo   = sx[0][kh ^ 1][headq][l31];
  const float to   = sx[1][kh ^ 1][headq][l31];
  const float lo2  = sx[2][kh ^ 1][headq][l31];
  const float tmax = fmaxf(tmaxh, to);
  const float fsA  = __expf(m - tmax);          // own-half scale to true max
  const float ltot = lw * fsA + lo2 * __expf(mo - tmax);

  float* mbuf = reinterpret_cast<float*>(&smem[0]);   // 64KB = 4 heads x 32q x 128d
  if (kh == 1) {
#pragma unroll
    for (int r = 0; r < 16; ++r) {
      const int row = (r & 3) + 8 * (r >> 2) + 4 * hiK;
      const float sfr = __shfl(fsA, row, 64);
#pragma unroll
      for (int dg = 0; dg < 4; ++dg)
        mbuf[headq * 4096 + row * 128 + dg * 32 + l31] = acc[dg][r] * sfr;
    }
  }
  __syncthreads();
  if (kh == 0) {
#pragma unroll
    for (int r = 0; r < 16; ++r) {
      const int row = (r & 3) + 8 * (r >> 2) + 4 * hiK;
      const float sfr = __shfl(fsA, row, 64);
      const size_t ob = ((size_t)(qbase + row) * NH + head) * DD + l31;
#pragma unroll
      for (int dg = 0; dg < 4; ++dg)
        O[ob + dg * 32] = acc[dg][r] * sfr + mbuf[headq * 4096 + row * 128 + dg * 32 + l31];
    }
    if (lane < 32) {
      Mo[(size_t)q * NH + head] = tmax;
      Lo[(size_t)q * NH + head] = ltot;
    }
  }
}

extern "C" void kernel_launch(void* const* d_in, const int* in_sizes, int n_in,
                              void* d_out, int out_size, void* d_ws, size_t ws_size,
                              hipStream_t stream) {
  const float* Q = (const float*)d_in[0];
  const float* K = (const float*)d_in[1];
  const float* V = (const float*)d_in[2];
  float* O  = (float*)d_out;
  float* Mo = O + (size_t)TT * NH * DD;
  float* Lo = Mo + (size_t)TT * NH;
  short* Kbf  = (short*)d_ws;                          // 4 MB
  short* Vtbf = Kbf + (size_t)NKV * TT * DD;           // 4 MB
  preconv<<<dim3(512), dim3(256), 0, stream>>>(K, V, Kbf, Vtbf);
  attn_fwd<<<dim3(64 * NKV), dim3(512), 0, stream>>>(Q, Kbf, Vtbf, O, Mo, Lo);
}

// Round 21
// 77.194 us; speedup vs baseline: 1.0466x; 1.0012x over previous
//
#include <hip/hip_runtime.h>
#include <hip/hip_bf16.h>

#define TT  2048
#define NH  32
#define NKV 8
#define DD  128
#define KVB 128         // keys per LDS tile (halves barrier count vs 64)
#define THR 8.0f        // defer-max rescale threshold (T13)

typedef __attribute__((ext_vector_type(8)))  short  short8;
typedef __attribute__((ext_vector_type(4)))  float  f32x4;
typedef __attribute__((ext_vector_type(16))) float  f32x16;
typedef unsigned int u32;
typedef __attribute__((ext_vector_type(4)))  u32    u32x4;

static __device__ __forceinline__ short f2bf(float x) {
  __bf16 b = (__bf16)x;                 // RNE f32->bf16
  return __builtin_bit_cast(short, b);
}
static __device__ __forceinline__ short8 cvt8(f32x4 a, f32x4 b) {
  short8 r;
  r[0]=f2bf(a[0]); r[1]=f2bf(a[1]); r[2]=f2bf(a[2]); r[3]=f2bf(a[3]);
  r[4]=f2bf(b[0]); r[5]=f2bf(b[1]); r[6]=f2bf(b[2]); r[7]=f2bf(b[3]);
  return r;
}
static __device__ __forceinline__ u32 pk2(float lo, float hi) {
  const u32 a = (u32)(unsigned short)f2bf(lo);
  const u32 b = (u32)(unsigned short)f2bf(hi);
  return a | (b << 16);
}
static __device__ __forceinline__ void gload_lds16(const short* g, short* l) {
  __builtin_amdgcn_global_load_lds(
      (const __attribute__((address_space(1))) u32*)g,
      (__attribute__((address_space(3))) u32*)l, 16, 0, 0);
}

// ---------------- pre-pass: K -> bf16 [kvh][j][d]; V -> bf16 transposed [kvh][d][j] ----
__global__ __launch_bounds__(256) void preconv(
    const float* __restrict__ K, const float* __restrict__ V,
    short* __restrict__ Kbf, short* __restrict__ Vtbf)
{
  const int t = threadIdx.x;
  if (blockIdx.x >= 256) {
    const int b  = blockIdx.x - 256;
    const int rr = (b << 6) + (t >> 2);      // rr = j*8+kvh
    const int q  = t & 3;
    const int j = rr >> 3, kvh = rr & 7;
    const float* src = K + (size_t)rr * DD + q * 32;
    short* dst = Kbf + ((size_t)kvh * TT + j) * DD + q * 32;
#pragma unroll
    for (int i = 0; i < 4; ++i) {
      f32x4 a  = *reinterpret_cast<const f32x4*>(src + i * 8);
      f32x4 bb = *reinterpret_cast<const f32x4*>(src + i * 8 + 4);
      *reinterpret_cast<short8*>(dst + i * 8) = cvt8(a, bb);
    }
  } else {
    const int kvh = blockIdx.x >> 5, jt = blockIdx.x & 31;
    __shared__ short Vl[64][136];
    const int jl = t >> 2, q = t & 3;
    const float* src = V + ((size_t)(jt * 64 + jl) * NKV + kvh) * DD + q * 32;
#pragma unroll
    for (int i = 0; i < 4; ++i) {
      f32x4 a  = *reinterpret_cast<const f32x4*>(src + i * 8);
      f32x4 bb = *reinterpret_cast<const f32x4*>(src + i * 8 + 4);
      *reinterpret_cast<short8*>(&Vl[jl][q * 32 + i * 8]) = cvt8(a, bb);
    }
    __syncthreads();
    const int d = t >> 1, jh = t & 1;
    short8 o[4];
#pragma unroll
    for (int k = 0; k < 4; ++k)
#pragma unroll
      for (int i = 0; i < 8; ++i)
        o[k][i] = Vl[jh * 32 + k * 8 + i][d];
    short* dst = Vtbf + ((size_t)kvh * DD + d) * TT + jt * 64 + jh * 32;
#pragma unroll
    for (int k = 0; k < 4; ++k)
      *reinterpret_cast<short8*>(dst + k * 8) = o[k];
  }
}

// ---------------- main attention kernel ------------------------------------------
// r20 body (77.29us: r14 minus setprio) with ONE change: QK^T accumulator split
// into EVEN/ODD k-slice partial chains. Rationale: per wave, QK was 2 independent
// chains of 8 DEPENDENT MFMAs; at 2 waves/SIMD only 4 chains cover the 32x32x16
// dependent-issue latency. Splitting each into even-ks/odd-ks partials gives 4
// chains of 4 per wave (8/SIMD), halving exposed chain depth; the two partials
// are merged with one f32x16 add per kg (order-only FP change, exact in f32).
// Everything else r20-verbatim: KVB=128, 8 waves = 4 GQA heads x 2 key-halves,
// per-half online softmax with defer-max THR=8, DMA after QK^T (r13: before is
// -6%), single __syncthreads per tile (r18: split drain -4%), no setprio (r20:
// lockstep-null, slight +), sx/mbuf epilogue, heavies-first grid order, K/V dbuf
// via global_load_lds with 16B-chunk XOR swizzle (phys = logical ^ (row&7)).
// MFMA 32x32x16 layouts: A: lane=A[row=l&31][k=8*(l>>5)+i];
// B: B[k=8*(l>>5)+i][col=l&31]; C/D: col=l&31, row=(reg&3)+8*(reg>>2)+4*(l>>5).
__global__ __launch_bounds__(512, 2) void attn_fwd(
    const float* __restrict__ Q, const short* __restrict__ Kbf,
    const short* __restrict__ Vtbf, float* __restrict__ O,
    float* __restrict__ Mo, float* __restrict__ Lo)
{
  __shared__ __align__(16) short smem[2*KVB*DD + 2*DD*KVB];  // 128KB: Kb | Vt
  __shared__ float sx[3][2][4][32];                          // m / tmax / lsum exchange

  short (*Kb)[KVB][DD] = reinterpret_cast<short(*)[KVB][DD]>(&smem[0]);
  short (*Vt)[DD][KVB] = reinterpret_cast<short(*)[DD][KVB]>(&smem[2*KVB*DD]);

  const int bid  = blockIdx.x;
  const int kvh  = bid & (NKV - 1);          // kvh == XCD id under round-robin
  const int q32  = 63 - (bid >> 3);          // heavies first, lights after: LPT queue
  const int wv   = threadIdx.x >> 6;         // 0..7
  const int headq= wv & 3;
  const int kh   = wv >> 2;                  // key half: keys [64kh, 64kh+64) per tile
  const int lane = threadIdx.x & 63;
  const int l31  = lane & 31;
  const int hiK  = lane >> 5;
  const int l7   = lane & 7;
  const int head = kvh * 4 + headq;
  const int qbase = q32 * 32;
  const int q    = qbase + l31;              // this lane's q-column

  // ---- staging offsets: wave stages K rows and V d-rows [16wv, 16wv+16) ----
  int koff[4], voff[4];
#pragma unroll
  for (int t = 0; t < 4; ++t) {
    const int row = 16 * wv + 4 * t + (lane >> 4);
    const int sw  = (lane & 15) ^ (4 * (t & 1) + (lane >> 4));
    koff[t] = row * DD + sw * 8;
    voff[t] = row * TT + sw * 8;
  }

  // ---- Q B-frags: lane holds Q[qbase+l31][ks*16 + 8*hiK + i], ks=0..7 ----
  short8 aq[8];
  {
    const float* qp = Q + ((size_t)q * NH + head) * DD + hiK * 8;
#pragma unroll
    for (int ks = 0; ks < 8; ++ks) {
      const float* p = qp + ks * 16;
      aq[ks] = cvt8(*reinterpret_cast<const f32x4*>(p),
                    *reinterpret_cast<const f32x4*>(p + 4));
    }
  }

  f32x16 acc[4];
#pragma unroll
  for (int i = 0; i < 4; ++i) acc[i] = (f32x16)0.0f;
  float m = -INFINITY, tmaxh = -INFINITY, lsum = 0.0f;

  const int ntiles = (q32 + 4) >> 2;   // ceil((qbase+32)/128)

  const short* kgp = Kbf + (size_t)kvh * TT * DD;
  const short* vgp = Vtbf + (size_t)kvh * DD * TT;

  // ---- prologue: DMA tile 0 into buffer 0 ----
#pragma unroll
  for (int t = 0; t < 4; ++t)
    gload_lds16(kgp + koff[t], &Kb[0][16 * wv + 4 * t][0]);
#pragma unroll
  for (int t = 0; t < 4; ++t)
    gload_lds16(vgp + voff[t], &Vt[0][16 * wv + 4 * t][0]);
  kgp += (size_t)KVB * DD;
  vgp += KVB;

  for (int jt = 0; jt < ntiles; ++jt) {
    const int j0  = jt << 7;
    const int buf = jt & 1;

    __syncthreads();   // drains own DMA (vmcnt0); prev buffer free for overwrite

    // ---- QK^T on this wave's 64-key half, 4 partial chains (even/odd ks x kg) ----
    f32x16 st[2];
    {
      f32x16 se[2], so[2];
      se[0] = (f32x16)0.0f; se[1] = (f32x16)0.0f;
      so[0] = (f32x16)0.0f; so[1] = (f32x16)0.0f;
#pragma unroll
      for (int kg = 0; kg < 2; ++kg) {
        const short* kr = &Kb[buf][kh * 64 + kg * 32 + l31][0];
#pragma unroll
        for (int kp = 0; kp < 4; ++kp) {
          const int ksE = 2 * kp;          // even k-slices: 0,2,4,6
          const int ksO = 2 * kp + 1;      // odd  k-slices: 1,3,5,7
          const int cE = ((ksE << 1) | hiK) ^ l7;
          const int cO = ((ksO << 1) | hiK) ^ l7;
          short8 kbE = *reinterpret_cast<const short8*>(kr + cE * 8);
          short8 kbO = *reinterpret_cast<const short8*>(kr + cO * 8);
          se[kg] = __builtin_amdgcn_mfma_f32_32x32x16_bf16(kbE, aq[ksE], se[kg], 0, 0, 0);
          so[kg] = __builtin_amdgcn_mfma_f32_32x32x16_bf16(kbO, aq[ksO], so[kg], 0, 0, 0);
        }
      }
      st[0] = se[0] + so[0];
      st[1] = se[1] + so[1];
    }

    // ---- DMA tile jt+1 into buf^1 (r7/r13-proven placement: after QK^T) ----
    if (jt + 1 < ntiles) {
      const int nb = buf ^ 1;
#pragma unroll
      for (int t = 0; t < 4; ++t)
        gload_lds16(kgp + koff[t], &Kb[nb][16 * wv + 4 * t][0]);
#pragma unroll
      for (int t = 0; t < 4; ++t)
        gload_lds16(vgp + voff[t], &Vt[nb][16 * wv + 4 * t][0]);
      kgp += (size_t)KVB * DD;
      vgp += KVB;
    }

    // ---- causal mask: only the last tile can cross the diagonal ----
    if (jt == ntiles - 1) {
#pragma unroll
      for (int kg = 0; kg < 2; ++kg)
#pragma unroll
        for (int r = 0; r < 16; ++r) {
          const int key = j0 + kh * 64 + kg * 32 + (r & 3) + 8 * (r >> 2) + 4 * hiK;
          if (key > q) st[kg][r] = -1.0e10f;
        }
    }

    // ---- half max (lane-local over 64 keys + lane^32 merge) ----
    float mx = fmaxf(st[0][0], st[1][0]);
#pragma unroll
    for (int r = 1; r < 16; ++r) mx = fmaxf(mx, fmaxf(st[0][r], st[1][r]));
    mx = fmaxf(mx, __shfl_xor(mx, 32, 64));
    tmaxh = fmaxf(tmaxh, mx);

    // ---- defer-max: rescale only when the running max grows by >THR ----
    if (__any(mx > m + THR)) {
      const float mn = fmaxf(m, mx);
      const float sc = __expf(m - mn);
      m = mn;
      lsum *= sc;
#pragma unroll
      for (int r = 0; r < 16; ++r) {
        const float sf = __shfl(sc, (r & 3) + 8 * (r >> 2) + 4 * hiK, 64);
        acc[0][r] *= sf; acc[1][r] *= sf; acc[2][r] *= sf; acc[3][r] *= sf;
      }
    }

    // ---- P = exp(S-m); pack to PV A-frags via lane^32 exchange ----
    short8 pa[4];
#pragma unroll
    for (int kg = 0; kg < 2; ++kg) {
      float e[16];
#pragma unroll
      for (int r = 0; r < 16; ++r) e[r] = __expf(st[kg][r] - m);
      lsum += (((e[0]+e[1])+(e[2]+e[3]))+((e[4]+e[5])+(e[6]+e[7])))
            + (((e[8]+e[9])+(e[10]+e[11]))+((e[12]+e[13])+(e[14]+e[15])));
#pragma unroll
      for (int h2 = 0; h2 < 2; ++h2) {
        const int b = 8 * h2;
        u32 u0 = pk2(e[b+0], e[b+1]);
        u32 u1 = pk2(e[b+2], e[b+3]);
        u32 u2 = pk2(e[b+4], e[b+5]);
        u32 u3 = pk2(e[b+6], e[b+7]);
        u32 sA = hiK ? u0 : u2;
        u32 sB = hiK ? u1 : u3;
        u32 rA = __shfl_xor(sA, 32, 64);
        u32 rB = __shfl_xor(sB, 32, 64);
        u32x4 w4;
        w4[0] = hiK ? rA : u0;
        w4[1] = hiK ? rB : u1;
        w4[2] = hiK ? u2 : rA;
        w4[3] = hiK ? u3 : rB;
        pa[kg * 2 + h2] = __builtin_bit_cast(short8, w4);
      }
    }

    // ---- P @ V over this wave's 4 key-slices of 16 (keys kh*64 + 16pi) ----
#pragma unroll
    for (int dg = 0; dg < 4; ++dg) {
      const short* vr = &Vt[buf][dg * 32 + l31][0];
#pragma unroll
      for (int pi = 0; pi < 4; ++pi) {
        const int c = (8 * kh + 2 * pi + hiK) ^ l7;
        short8 vb = *reinterpret_cast<const short8*>(vr + c * 8);
        acc[dg] = __builtin_amdgcn_mfma_f32_32x32x16_bf16(pa[pi], vb, acc[dg], 0, 0, 0);
      }
    }
  }

  // ---- epilogue: merge the two key-halves ----
  const float lw = lsum + __shfl_xor(lsum, 32, 64);
  __syncthreads();                     // all PV done; K/V LDS is dead now
  if (lane < 32) {
    sx[0][kh][headq][lane] = m;
    sx[1][kh][headq][lane] = tmaxh;
    sx[2][kh][headq][lane] = lw;
  }
  __syncthreads();
  const float mo   = sx[0][kh ^ 1][headq][l31];
  const float to   = sx[1][kh ^ 1][headq][l31];
  const float lo2  = sx[2][kh ^ 1][headq][l31];
  const float tmax = fmaxf(tmaxh, to);
  const float fsA  = __expf(m - tmax);          // own-half scale to true max
  const float ltot = lw * fsA + lo2 * __expf(mo - tmax);

  float* mbuf = reinterpret_cast<float*>(&smem[0]);   // 64KB = 4 heads x 32q x 128d
  if (kh == 1) {
#pragma unroll
    for (int r = 0; r < 16; ++r) {
      const int row = (r & 3) + 8 * (r >> 2) + 4 * hiK;
      const float sfr = __shfl(fsA, row, 64);
#pragma unroll
      for (int dg = 0; dg < 4; ++dg)
        mbuf[headq * 4096 + row * 128 + dg * 32 + l31] = acc[dg][r] * sfr;
    }
  }
  __syncthreads();
  if (kh == 0) {
#pragma unroll
    for (int r = 0; r < 16; ++r) {
      const int row = (r & 3) + 8 * (r >> 2) + 4 * hiK;
      const float sfr = __shfl(fsA, row, 64);
      const size_t ob = ((size_t)(qbase + row) * NH + head) * DD + l31;
#pragma unroll
      for (int dg = 0; dg < 4; ++dg)
        O[ob + dg * 32] = acc[dg][r] * sfr + mbuf[headq * 4096 + row * 128 + dg * 32 + l31];
    }
    if (lane < 32) {
      Mo[(size_t)q * NH + head] = tmax;
      Lo[(size_t)q * NH + head] = ltot;
    }
  }
}

extern "C" void kernel_launch(void* const* d_in, const int* in_sizes, int n_in,
                              void* d_out, int out_size, void* d_ws, size_t ws_size,
                              hipStream_t stream) {
  const float* Q = (const float*)d_in[0];
  const float* K = (const float*)d_in[1];
  const float* V = (const float*)d_in[2];
  float* O  = (float*)d_out;
  float* Mo = O + (size_t)TT * NH * DD;
  float* Lo = Mo + (size_t)TT * NH;
  short* Kbf  = (short*)d_ws;                          // 4 MB
  short* Vtbf = Kbf + (size_t)NKV * TT * DD;           // 4 MB
  preconv<<<dim3(512), dim3(256), 0, stream>>>(K, V, Kbf, Vtbf);
  attn_fwd<<<dim3(64 * NKV), dim3(512), 0, stream>>>(Q, Kbf, Vtbf, O, Mo, Lo);
}

// Round 22
// 77.159 us; speedup vs baseline: 1.0471x; 1.0005x over previous
//
#include <hip/hip_runtime.h>
#include <hip/hip_bf16.h>

#define TT  2048
#define NH  32
#define NKV 8
#define DD  128
#define KVB 128         // keys per LDS tile (halves barrier count vs 64)
#define THR 8.0f        // defer-max rescale threshold (T13)

typedef __attribute__((ext_vector_type(8)))  short  short8;
typedef __attribute__((ext_vector_type(4)))  float  f32x4;
typedef __attribute__((ext_vector_type(16))) float  f32x16;
typedef unsigned int u32;
typedef __attribute__((ext_vector_type(4)))  u32    u32x4;

static __device__ __forceinline__ short f2bf(float x) {
  __bf16 b = (__bf16)x;                 // RNE f32->bf16
  return __builtin_bit_cast(short, b);
}
static __device__ __forceinline__ short8 cvt8(f32x4 a, f32x4 b) {
  short8 r;
  r[0]=f2bf(a[0]); r[1]=f2bf(a[1]); r[2]=f2bf(a[2]); r[3]=f2bf(a[3]);
  r[4]=f2bf(b[0]); r[5]=f2bf(b[1]); r[6]=f2bf(b[2]); r[7]=f2bf(b[3]);
  return r;
}
static __device__ __forceinline__ u32 pk2(float lo, float hi) {
  const u32 a = (u32)(unsigned short)f2bf(lo);
  const u32 b = (u32)(unsigned short)f2bf(hi);
  return a | (b << 16);
}
static __device__ __forceinline__ void gload_lds16(const short* g, short* l) {
  __builtin_amdgcn_global_load_lds(
      (const __attribute__((address_space(1))) u32*)g,
      (__attribute__((address_space(3))) u32*)l, 16, 0, 0);
}

// ---------------- pre-pass: K -> bf16 [kvh][j][d]; V -> bf16 transposed [kvh][d][j] ----
__global__ __launch_bounds__(256) void preconv(
    const float* __restrict__ K, const float* __restrict__ V,
    short* __restrict__ Kbf, short* __restrict__ Vtbf)
{
  const int t = threadIdx.x;
  if (blockIdx.x >= 256) {
    const int b  = blockIdx.x - 256;
    const int rr = (b << 6) + (t >> 2);      // rr = j*8+kvh
    const int q  = t & 3;
    const int j = rr >> 3, kvh = rr & 7;
    const float* src = K + (size_t)rr * DD + q * 32;
    short* dst = Kbf + ((size_t)kvh * TT + j) * DD + q * 32;
#pragma unroll
    for (int i = 0; i < 4; ++i) {
      f32x4 a  = *reinterpret_cast<const f32x4*>(src + i * 8);
      f32x4 bb = *reinterpret_cast<const f32x4*>(src + i * 8 + 4);
      *reinterpret_cast<short8*>(dst + i * 8) = cvt8(a, bb);
    }
  } else {
    const int kvh = blockIdx.x >> 5, jt = blockIdx.x & 31;
    __shared__ short Vl[64][136];
    const int jl = t >> 2, q = t & 3;
    const float* src = V + ((size_t)(jt * 64 + jl) * NKV + kvh) * DD + q * 32;
#pragma unroll
    for (int i = 0; i < 4; ++i) {
      f32x4 a  = *reinterpret_cast<const f32x4*>(src + i * 8);
      f32x4 bb = *reinterpret_cast<const f32x4*>(src + i * 8 + 4);
      *reinterpret_cast<short8*>(&Vl[jl][q * 32 + i * 8]) = cvt8(a, bb);
    }
    __syncthreads();
    const int d = t >> 1, jh = t & 1;
    short8 o[4];
#pragma unroll
    for (int k = 0; k < 4; ++k)
#pragma unroll
      for (int i = 0; i < 8; ++i)
        o[k][i] = Vl[jh * 32 + k * 8 + i][d];
    short* dst = Vtbf + ((size_t)kvh * DD + d) * TT + jt * 64 + jh * 32;
#pragma unroll
    for (int k = 0; k < 4; ++k)
      *reinterpret_cast<short8*>(dst + k * 8) = o[k];
  }
}

// ---------------- main attention kernel ------------------------------------------
// SESSION-FINAL STRUCTURE (r14 @77.6us -> r20 -setprio @77.3 -> r21 +QK ILP split
// @77.2) with the LAST zero-risk micro-opt: T17 BALANCED TREE MAX.
// The 32-value tile max was a SERIAL 16-step accumulation (dep depth ~16 x 4cy
// ~ 64cy naked on the QK->exp critical path each tile); rewritten as a balanced
// tree (depth 5; nested fmaxf triples fuse to v_max3_f32 per T17). Max is
// order-independent -> bit-identical results.
// Structure recap: KVB=128, 8 waves = 4 GQA heads x 2 key-halves, per-half
// online softmax with defer-max THR=8; DMA after QK^T (r13: before is -6%);
// single __syncthreads/tile (r18: split drain -4%); no setprio (r20: lockstep
// null); QK even/odd partial chains (r21: null, kept); sx/mbuf epilogue;
// heavies-first grid = LPT queue under greedy backfill (r10/r15/r16: explicit
// balance ties or spills); K/V dbuf via global_load_lds + 16B-chunk XOR swizzle
// (phys = logical ^ (row&7)) pre-applied on the per-lane GLOBAL source address.
// MFMA 32x32x16 layouts: A: lane=A[row=l&31][k=8*(l>>5)+i];
// B: B[k=8*(l>>5)+i][col=l&31]; C/D: col=l&31, row=(reg&3)+8*(reg>>2)+4*(l>>5).
__global__ __launch_bounds__(512, 2) void attn_fwd(
    const float* __restrict__ Q, const short* __restrict__ Kbf,
    const short* __restrict__ Vtbf, float* __restrict__ O,
    float* __restrict__ Mo, float* __restrict__ Lo)
{
  __shared__ __align__(16) short smem[2*KVB*DD + 2*DD*KVB];  // 128KB: Kb | Vt
  __shared__ float sx[3][2][4][32];                          // m / tmax / lsum exchange

  short (*Kb)[KVB][DD] = reinterpret_cast<short(*)[KVB][DD]>(&smem[0]);
  short (*Vt)[DD][KVB] = reinterpret_cast<short(*)[DD][KVB]>(&smem[2*KVB*DD]);

  const int bid  = blockIdx.x;
  const int kvh  = bid & (NKV - 1);          // kvh == XCD id under round-robin
  const int q32  = 63 - (bid >> 3);          // heavies first, lights after: LPT queue
  const int wv   = threadIdx.x >> 6;         // 0..7
  const int headq= wv & 3;
  const int kh   = wv >> 2;                  // key half: keys [64kh, 64kh+64) per tile
  const int lane = threadIdx.x & 63;
  const int l31  = lane & 31;
  const int hiK  = lane >> 5;
  const int l7   = lane & 7;
  const int head = kvh * 4 + headq;
  const int qbase = q32 * 32;
  const int q    = qbase + l31;              // this lane's q-column

  // ---- staging offsets: wave stages K rows and V d-rows [16wv, 16wv+16) ----
  int koff[4], voff[4];
#pragma unroll
  for (int t = 0; t < 4; ++t) {
    const int row = 16 * wv + 4 * t + (lane >> 4);
    const int sw  = (lane & 15) ^ (4 * (t & 1) + (lane >> 4));
    koff[t] = row * DD + sw * 8;
    voff[t] = row * TT + sw * 8;
  }

  // ---- Q B-frags: lane holds Q[qbase+l31][ks*16 + 8*hiK + i], ks=0..7 ----
  short8 aq[8];
  {
    const float* qp = Q + ((size_t)q * NH + head) * DD + hiK * 8;
#pragma unroll
    for (int ks = 0; ks < 8; ++ks) {
      const float* p = qp + ks * 16;
      aq[ks] = cvt8(*reinterpret_cast<const f32x4*>(p),
                    *reinterpret_cast<const f32x4*>(p + 4));
    }
  }

  f32x16 acc[4];
#pragma unroll
  for (int i = 0; i < 4; ++i) acc[i] = (f32x16)0.0f;
  float m = -INFINITY, tmaxh = -INFINITY, lsum = 0.0f;

  const int ntiles = (q32 + 4) >> 2;   // ceil((qbase+32)/128)

  const short* kgp = Kbf + (size_t)kvh * TT * DD;
  const short* vgp = Vtbf + (size_t)kvh * DD * TT;

  // ---- prologue: DMA tile 0 into buffer 0 ----
#pragma unroll
  for (int t = 0; t < 4; ++t)
    gload_lds16(kgp + koff[t], &Kb[0][16 * wv + 4 * t][0]);
#pragma unroll
  for (int t = 0; t < 4; ++t)
    gload_lds16(vgp + voff[t], &Vt[0][16 * wv + 4 * t][0]);
  kgp += (size_t)KVB * DD;
  vgp += KVB;

  for (int jt = 0; jt < ntiles; ++jt) {
    const int j0  = jt << 7;
    const int buf = jt & 1;

    __syncthreads();   // drains own DMA (vmcnt0); prev buffer free for overwrite

    // ---- QK^T on this wave's 64-key half, 4 partial chains (even/odd ks x kg) ----
    f32x16 st[2];
    {
      f32x16 se[2], so[2];
      se[0] = (f32x16)0.0f; se[1] = (f32x16)0.0f;
      so[0] = (f32x16)0.0f; so[1] = (f32x16)0.0f;
#pragma unroll
      for (int kg = 0; kg < 2; ++kg) {
        const short* kr = &Kb[buf][kh * 64 + kg * 32 + l31][0];
#pragma unroll
        for (int kp = 0; kp < 4; ++kp) {
          const int ksE = 2 * kp;          // even k-slices: 0,2,4,6
          const int ksO = 2 * kp + 1;      // odd  k-slices: 1,3,5,7
          const int cE = ((ksE << 1) | hiK) ^ l7;
          const int cO = ((ksO << 1) | hiK) ^ l7;
          short8 kbE = *reinterpret_cast<const short8*>(kr + cE * 8);
          short8 kbO = *reinterpret_cast<const short8*>(kr + cO * 8);
          se[kg] = __builtin_amdgcn_mfma_f32_32x32x16_bf16(kbE, aq[ksE], se[kg], 0, 0, 0);
          so[kg] = __builtin_amdgcn_mfma_f32_32x32x16_bf16(kbO, aq[ksO], so[kg], 0, 0, 0);
        }
      }
      st[0] = se[0] + so[0];
      st[1] = se[1] + so[1];
    }

    // ---- DMA tile jt+1 into buf^1 (r7/r13-proven placement: after QK^T) ----
    if (jt + 1 < ntiles) {
      const int nb = buf ^ 1;
#pragma unroll
      for (int t = 0; t < 4; ++t)
        gload_lds16(kgp + koff[t], &Kb[nb][16 * wv + 4 * t][0]);
#pragma unroll
      for (int t = 0; t < 4; ++t)
        gload_lds16(vgp + voff[t], &Vt[nb][16 * wv + 4 * t][0]);
      kgp += (size_t)KVB * DD;
      vgp += KVB;
    }

    // ---- causal mask: only the last tile can cross the diagonal ----
    if (jt == ntiles - 1) {
#pragma unroll
      for (int kg = 0; kg < 2; ++kg)
#pragma unroll
        for (int r = 0; r < 16; ++r) {
          const int key = j0 + kh * 64 + kg * 32 + (r & 3) + 8 * (r >> 2) + 4 * hiK;
          if (key > q) st[kg][r] = -1.0e10f;
        }
    }

    // ---- half max: BALANCED TREE (T17; depth 5 vs serial 16; max3-fusable) ----
    float a16[16];
#pragma unroll
    for (int r = 0; r < 16; ++r) a16[r] = fmaxf(st[0][r], st[1][r]);
    float b4[4];
#pragma unroll
    for (int i = 0; i < 4; ++i)
      b4[i] = fmaxf(fmaxf(a16[4 * i], a16[4 * i + 1]),
                    fmaxf(a16[4 * i + 2], a16[4 * i + 3]));
    float mx = fmaxf(fmaxf(b4[0], b4[1]), fmaxf(b4[2], b4[3]));
    mx = fmaxf(mx, __shfl_xor(mx, 32, 64));
    tmaxh = fmaxf(tmaxh, mx);

    // ---- defer-max: rescale only when the running max grows by >THR ----
    if (__any(mx > m + THR)) {
      const float mn = fmaxf(m, mx);
      const float sc = __expf(m - mn);
      m = mn;
      lsum *= sc;
#pragma unroll
      for (int r = 0; r < 16; ++r) {
        const float sf = __shfl(sc, (r & 3) + 8 * (r >> 2) + 4 * hiK, 64);
        acc[0][r] *= sf; acc[1][r] *= sf; acc[2][r] *= sf; acc[3][r] *= sf;
      }
    }

    // ---- P = exp(S-m); pack to PV A-frags via lane^32 exchange ----
    short8 pa[4];
#pragma unroll
    for (int kg = 0; kg < 2; ++kg) {
      float e[16];
#pragma unroll
      for (int r = 0; r < 16; ++r) e[r] = __expf(st[kg][r] - m);
      lsum += (((e[0]+e[1])+(e[2]+e[3]))+((e[4]+e[5])+(e[6]+e[7])))
            + (((e[8]+e[9])+(e[10]+e[11]))+((e[12]+e[13])+(e[14]+e[15])));
#pragma unroll
      for (int h2 = 0; h2 < 2; ++h2) {
        const int b = 8 * h2;
        u32 u0 = pk2(e[b+0], e[b+1]);
        u32 u1 = pk2(e[b+2], e[b+3]);
        u32 u2 = pk2(e[b+4], e[b+5]);
        u32 u3 = pk2(e[b+6], e[b+7]);
        u32 sA = hiK ? u0 : u2;
        u32 sB = hiK ? u1 : u3;
        u32 rA = __shfl_xor(sA, 32, 64);
        u32 rB = __shfl_xor(sB, 32, 64);
        u32x4 w4;
        w4[0] = hiK ? rA : u0;
        w4[1] = hiK ? rB : u1;
        w4[2] = hiK ? u2 : rA;
        w4[3] = hiK ? u3 : rB;
        pa[kg * 2 + h2] = __builtin_bit_cast(short8, w4);
      }
    }

    // ---- P @ V over this wave's 4 key-slices of 16 (keys kh*64 + 16pi) ----
#pragma unroll
    for (int dg = 0; dg < 4; ++dg) {
      const short* vr = &Vt[buf][dg * 32 + l31][0];
#pragma unroll
      for (int pi = 0; pi < 4; ++pi) {
        const int c = (8 * kh + 2 * pi + hiK) ^ l7;
        short8 vb = *reinterpret_cast<const short8*>(vr + c * 8);
        acc[dg] = __builtin_amdgcn_mfma_f32_32x32x16_bf16(pa[pi], vb, acc[dg], 0, 0, 0);
      }
    }
  }

  // ---- epilogue: merge the two key-halves ----
  const float lw = lsum + __shfl_xor(lsum, 32, 64);
  __syncthreads();                     // all PV done; K/V LDS is dead now
  if (lane < 32) {
    sx[0][kh][headq][lane] = m;
    sx[1][kh][headq][lane] = tmaxh;
    sx[2][kh][headq][lane] = lw;
  }
  __syncthreads();
  const float mo   = sx[0][kh ^ 1][headq][l31];
  const float to   = sx[1][kh ^ 1][headq][l31];
  const float lo2  = sx[2][kh ^ 1][headq][l31];
  const float tmax = fmaxf(tmaxh, to);
  const float fsA  = __expf(m - tmax);          // own-half scale to true max
  const float ltot = lw * fsA + lo2 * __expf(mo - tmax);

  float* mbuf = reinterpret_cast<float*>(&smem[0]);   // 64KB = 4 heads x 32q x 128d
  if (kh == 1) {
#pragma unroll
    for (int r = 0; r < 16; ++r) {
      const int row = (r & 3) + 8 * (r >> 2) + 4 * hiK;
      const float sfr = __shfl(fsA, row, 64);
#pragma unroll
      for (int dg = 0; dg < 4; ++dg)
        mbuf[headq * 4096 + row * 128 + dg * 32 + l31] = acc[dg][r] * sfr;
    }
  }
  __syncthreads();
  if (kh == 0) {
#pragma unroll
    for (int r = 0; r < 16; ++r) {
      const int row = (r & 3) + 8 * (r >> 2) + 4 * hiK;
      const float sfr = __shfl(fsA, row, 64);
      const size_t ob = ((size_t)(qbase + row) * NH + head) * DD + l31;
#pragma unroll
      for (int dg = 0; dg < 4; ++dg)
        O[ob + dg * 32] = acc[dg][r] * sfr + mbuf[headq * 4096 + row * 128 + dg * 32 + l31];
    }
    if (lane < 32) {
      Mo[(size_t)q * NH + head] = tmax;
      Lo[(size_t)q * NH + head] = ltot;
    }
  }
}

extern "C" void kernel_launch(void* const* d_in, const int* in_sizes, int n_in,
                              void* d_out, int out_size, void* d_ws, size_t ws_size,
                              hipStream_t stream) {
  const float* Q = (const float*)d_in[0];
  const float* K = (const float*)d_in[1];
  const float* V = (const float*)d_in[2];
  float* O  = (float*)d_out;
  float* Mo = O + (size_t)TT * NH * DD;
  float* Lo = Mo + (size_t)TT * NH;
  short* Kbf  = (short*)d_ws;                          // 4 MB
  short* Vtbf = Kbf + (size_t)NKV * TT * DD;           // 4 MB
  preconv<<<dim3(512), dim3(256), 0, stream>>>(K, V, Kbf, Vtbf);
  attn_fwd<<<dim3(64 * NKV), dim3(512), 0, stream>>>(Q, Kbf, Vtbf, O, Mo, Lo);
}